// Round 7
// baseline (277.556 us; speedup 1.0000x reference)
//
#include <hip/hip_runtime.h>
#include <hip/hip_bf16.h>
#include <stdint.h>

typedef unsigned short u16;
typedef __attribute__((ext_vector_type(8))) short short8;
typedef __attribute__((ext_vector_type(4))) short short4v;
typedef __attribute__((ext_vector_type(4))) float f32x4;

#define MFMA16(a,b,c) __builtin_amdgcn_mfma_f32_16x16x32_bf16((a),(b),(c),0,0,0)
#define EXP2F(x) __builtin_amdgcn_exp2f(x)

typedef const __attribute__((address_space(1))) void glb_void;
typedef __attribute__((address_space(3))) void lds_void;

__device__ __forceinline__ u16 f2b(float f){
  unsigned u = __float_as_uint(f);
  u += 0x7fffu + ((u>>16)&1u);
  return (u16)(u>>16);
}
__device__ __forceinline__ unsigned pack_bf16(float a, float b){
  __hip_bfloat162 h = __float22bfloat162_rn(make_float2(a,b));
  unsigned u; __builtin_memcpy(&u, &h, 4); return u;
}
__device__ __forceinline__ void gld16(const void* g, void* l){
  __builtin_amdgcn_global_load_lds((glb_void*)g, (lds_void*)l, 16, 0, 0);
}

// ---- swizzled staging: LDS[row][c] = G[row][ (c/8 ^ (row&7))*8 + c%8 ] ----
__device__ __forceinline__ void stage128x64_sw(const u16* g, u16* lds, int gstride, int w, int lane){
  const int sub = lane>>3, c16 = lane&7;
  const int gcol = (c16 ^ sub)<<3;
  #pragma unroll
  for (int i=0;i<4;++i){
    int r0 = (w*4+i)*8;
    gld16(g + (size_t)(r0 + sub)*gstride + gcol, lds + r0*64);
  }
}
__device__ __forceinline__ void stage64x64_sw(const u16* g, u16* lds, int gstride, int w, int lane){
  const int sub = lane>>3, c16 = lane&7;
  const int gcol = (c16 ^ sub)<<3;
  #pragma unroll
  for (int i=0;i<2;++i){
    int r0 = (w*2+i)*8;
    gld16(g + (size_t)(r0 + sub)*gstride + gcol, lds + r0*64);
  }
}
__device__ __forceinline__ const short8* frag64(const u16* lds, int row, int c16){
  return (const short8*)(lds + row*64 + ((c16 ^ (row&7))<<3));
}
__device__ __forceinline__ void stage64x128_sw(const u16* g, u16* lds, int gstride, int w, int lane){
  const int sub = lane>>4, c16 = lane&15;
  #pragma unroll
  for (int i=0;i<4;++i){
    int r0 = (w*4+i)*4;
    int row = r0 + sub;
    gld16(g + (size_t)row*gstride + ((c16 ^ (row&15))<<3), lds + r0*128);
  }
}
__device__ __forceinline__ const short8* frag128(const u16* lds, int row, int c16){
  return (const short8*)(lds + row*128 + ((c16 ^ (row&15))<<3));
}

// ================= PREP: weight cvt + mask classes + q/k/v transposes, one dispatch =======
__global__ __launch_bounds__(256) void prep(
    const float* __restrict__ q, const float* __restrict__ k, const float* __restrict__ v,
    const float* __restrict__ qkm, const float* __restrict__ km,
    const float* __restrict__ Wq, const float* __restrict__ Wk,
    const float* __restrict__ Wv, const float* __restrict__ Wo,
    u16* __restrict__ W16, char* __restrict__ classes,
    u16* __restrict__ qT, u16* __restrict__ kT, u16* __restrict__ vT)
{
  __shared__ __align__(16) float t[64][72];
  const int bx = blockIdx.x, tid = threadIdx.x;
  const int S = 2048, E = 1024, nW = E*E;

  if (bx < 2048){                      // ---- weight convert ----
    const int sel = bx>>9, blk = bx&511;
    const float* src = sel==0?Wq : sel==1?Wk : sel==2?Wv : Wo;
    const float sc = (sel==0) ? 0.18033688f : 1.0f;   // 0.125 * log2(e)
    u16* dst = W16 + (size_t)sel*nW;
    int i = (blk*256 + tid)*8;
    float4 a = *(const float4*)(src+i);
    float4 b = *(const float4*)(src+i+4);
    short8 o;
    o[0]=(short)f2b(a.x*sc); o[1]=(short)f2b(a.y*sc); o[2]=(short)f2b(a.z*sc); o[3]=(short)f2b(a.w*sc);
    o[4]=(short)f2b(b.x*sc); o[5]=(short)f2b(b.y*sc); o[6]=(short)f2b(b.z*sc); o[7]=(short)f2b(b.w*sc);
    *(short8*)(dst+i) = o;
  } else if (bx < 4096){               // ---- mask tile classification (64x64) ----
    const int tt = bx - 2048;
    const int b = tt>>10, qi = (tt>>5)&31, ki = tt&31;
    const int k0 = ki*64, q0 = qi*64;
    int az = 1, an = 1;
    #pragma unroll
    for (int p=0;p<4;++p){
      int e = tid + p*256;
      int row = e>>4, c4 = (e&15)*4;
      float kmv = km[(size_t)b*S + k0 + row];
      float4 mv = *(const float4*)&qkm[((size_t)b*S + k0 + row)*S + q0 + c4];
      mv.x += kmv; mv.y += kmv; mv.z += kmv; mv.w += kmv;
      az &= (mv.x==0.f) & (mv.y==0.f) & (mv.z==0.f) & (mv.w==0.f);
      an &= (mv.x<-1e3f) & (mv.y<-1e3f) & (mv.z<-1e3f) & (mv.w<-1e3f);
    }
    const int az_all = __syncthreads_and(az);
    const int an_all = __syncthreads_and(an);
    if (tid==0)
      classes[((size_t)b*32 + qi)*32 + ki] = an_all ? 2 : (az_all ? 0 : 1);
  } else {                             // ---- transpose+convert q/k/v ----
    const int tt = bx - 4096;
    const int tensor = tt>>10, r = tt&1023;
    const int b = r>>9, rr = r&511;
    const int c0 = (rr>>5)*64, s0 = (rr&31)*64;
    const float* x = tensor==0 ? q : tensor==1 ? k : v;
    u16* xt = tensor==0 ? qT : tensor==1 ? kT : vT;
    #pragma unroll
    for (int p=0;p<4;++p){
      int e = tid + p*256;
      int row = e>>4, c4 = (e&15)*4;
      *(float4*)&t[row][c4] = *(const float4*)&x[((size_t)b*E + c0 + row)*S + s0 + c4];
    }
    __syncthreads();
    #pragma unroll
    for (int p=0;p<2;++p){
      int e = tid + p*256;
      int row = e>>3, col8 = (e&7)*8;
      short8 o;
      #pragma unroll
      for (int u=0;u<8;++u) o[u] = (short)f2b(t[col8+u][row]);
      *(short8*)&xt[((size_t)b*S + s0 + row)*E + c0 + col8] = o;
    }
  }
}

// ---------------- GEMM core: C[M][N] = A[M][K]*Bt[N][K]^T + bias*bscale -------------------
template<bool F32OUT>
__device__ __forceinline__ void gemm_core(
    const u16* __restrict__ A, const u16* __restrict__ Bt, const float* __restrict__ bias,
    float bscale, void* __restrict__ Cv, size_t cbase, int N, int K, int bias_on_m,
    int m0, int n0, u16* As, u16* Bs)
{
  const int tid = threadIdx.x, w = tid>>6, lane = tid&63;
  const int ln = lane&15, quad = lane>>4;
  const int m0w = (w>>1)*64, n0w = (w&1)*64;
  f32x4 acc[4][4];
  #pragma unroll
  for(int i=0;i<4;++i)
    #pragma unroll
    for(int j=0;j<4;++j) acc[i][j] = f32x4{0.f,0.f,0.f,0.f};

  for (int kc=0; kc<K; kc+=64){
    __syncthreads();
    stage128x64_sw(A  + (size_t)m0*K + kc, As, K, w, lane);
    stage128x64_sw(Bt + (size_t)n0*K + kc, Bs, K, w, lane);
    __syncthreads();
    #pragma unroll
    for (int kk=0; kk<64; kk+=32){
      const int c16 = (kk>>3) + quad;
      short8 af[4], bf[4];
      #pragma unroll
      for (int mt=0;mt<4;++mt) af[mt] = *frag64(As, m0w+mt*16+ln, c16);
      #pragma unroll
      for (int nt=0;nt<4;++nt) bf[nt] = *frag64(Bs, n0w+nt*16+ln, c16);
      #pragma unroll
      for (int mt=0;mt<4;++mt)
        #pragma unroll
        for (int nt=0;nt<4;++nt)
          acc[mt][nt] = MFMA16(af[mt], bf[nt], acc[mt][nt]);
    }
  }
  #pragma unroll
  for (int mt=0;mt<4;++mt){
    #pragma unroll
    for (int nt=0;nt<4;++nt){
      const int col = n0 + n0w + nt*16 + ln;
      const float bn = bias_on_m ? 0.f : bias[col]*bscale;
      #pragma unroll
      for (int r=0;r<4;++r){
        const int row = m0 + m0w + mt*16 + quad*4 + r;
        const float bb = bias_on_m ? bias[row]*bscale : bn;
        const float val = acc[mt][nt][r] + bb;
        const size_t idx = cbase + (size_t)row*N + col;
        if (F32OUT) ((float*)Cv)[idx] = val;
        else        ((u16*)Cv)[idx]   = f2b(val);
      }
    }
  }
}

// ================= PROJ: Q,K,V projections in one uniform dispatch (768 blocks) ===========
__global__ __launch_bounds__(256,3) void proj(
    const u16* __restrict__ qT, const u16* __restrict__ kT, const u16* __restrict__ vT,
    const u16* __restrict__ W16,
    const float* __restrict__ bq, const float* __restrict__ bk, const float* __restrict__ bv,
    u16* __restrict__ Qb, u16* __restrict__ Kb, u16* __restrict__ Vb)
{
  __shared__ __align__(16) u16 As[128*64];
  __shared__ __align__(16) u16 Bs[128*64];
  const int bx = blockIdx.x;
  const int zone = bx>>7, r = bx&127;
  const size_t sSE = (size_t)2048*1024;
  const int nW = 1024*1024;
  if (zone < 4){
    const int sel = zone>>1, b = zone&1;
    const int m0 = (r>>3)*128, n0 = (r&7)*128;
    gemm_core<false>((sel? kT : qT) + b*sSE, W16 + (size_t)sel*nW, sel? bk : bq,
                     sel? 1.0f : 0.18033688f, sel? Kb : Qb, b*sSE,
                     1024, 1024, 0, m0, n0, As, Bs);
  } else {
    const int b = zone&1;
    const int m0 = (r>>4)*128, n0 = (r&15)*128;
    gemm_core<false>(W16 + (size_t)2*nW, vT + b*sSE, bv,
                     1.0f, Vb, b*sSE,
                     2048, 1024, 1, m0, n0, As, Bs);
  }
}

// ================= OUT GEMM: 64x128 tiles, split-K=2, atomic f32 accumulate ===============
// out[b][o][s] += Wo[o][c] * attnT[b][s][c]^T (+ bo on kh==0); grid (16,16,4), z = b*2+kh
__global__ __launch_bounds__(256,4) void gemm_out64(
    const u16* __restrict__ Wo16, const u16* __restrict__ At, const float* __restrict__ bo,
    float* __restrict__ out)
{
  __shared__ __align__(16) u16 As[64*64];
  __shared__ __align__(16) u16 Bs[128*64];
  const int zz = blockIdx.z, b = zz>>1, kh = zz&1;
  const int m0 = blockIdx.y*64, n0 = blockIdx.x*128;
  const size_t sSE = (size_t)2048*1024;
  const int K = 1024, N = 2048;
  const u16* Bt = At + b*sSE;
  const int tid = threadIdx.x, w = tid>>6, lane = tid&63;
  const int ln = lane&15, quad = lane>>4;
  const int m0w = (w>>1)*32, n0w = (w&1)*64;
  f32x4 acc[2][4];
  #pragma unroll
  for(int i=0;i<2;++i)
    #pragma unroll
    for(int j=0;j<4;++j) acc[i][j] = f32x4{0.f,0.f,0.f,0.f};

  for (int kc=kh*512; kc<kh*512+512; kc+=64){
    __syncthreads();
    stage64x64_sw (Wo16 + (size_t)m0*K + kc, As, K, w, lane);
    stage128x64_sw(Bt   + (size_t)n0*K + kc, Bs, K, w, lane);
    __syncthreads();
    #pragma unroll
    for (int kk=0; kk<64; kk+=32){
      const int c16 = (kk>>3) + quad;
      short8 af[2], bf[4];
      #pragma unroll
      for (int mt=0;mt<2;++mt) af[mt] = *frag64(As, m0w+mt*16+ln, c16);
      #pragma unroll
      for (int nt=0;nt<4;++nt) bf[nt] = *frag64(Bs, n0w+nt*16+ln, c16);
      #pragma unroll
      for (int mt=0;mt<2;++mt)
        #pragma unroll
        for (int nt=0;nt<4;++nt)
          acc[mt][nt] = MFMA16(af[mt], bf[nt], acc[mt][nt]);
    }
  }
  #pragma unroll
  for (int mt=0;mt<2;++mt){
    #pragma unroll
    for (int nt=0;nt<4;++nt){
      const int col = n0 + n0w + nt*16 + ln;
      #pragma unroll
      for (int r=0;r<4;++r){
        const int row = m0 + m0w + mt*16 + quad*4 + r;
        const float val = acc[mt][nt][r] + (kh ? 0.f : bo[row]);
        atomicAdd(&out[b*sSE + (size_t)row*N + col], val);
      }
    }
  }
}

// ================= fused flash attention: uniform-work blocks, paired k-tiles =============
__global__ __launch_bounds__(256,2) void attn(
    const u16* __restrict__ Qb, const u16* __restrict__ Kb, const u16* __restrict__ Vb,
    const float* __restrict__ qk_mask, const float* __restrict__ k_mask,
    const char* __restrict__ classes, u16* __restrict__ Ot)
{
  __shared__ __align__(16) u16 Ks[2][128*64];
  __shared__ __align__(16) u16 Vs[2][64*128];
  const int x = blockIdx.x;
  const int b = x&1, h = (x>>1)&15;
  const int pp = x>>5, pair = pp>>1, half = pp&1;
  const int tid = threadIdx.x, w = tid>>6, lane = tid&63;
  const int ln = lane&15, quad = lane>>4;
  const int S = 2048;
  const float LOG2E = 1.44269504f, C2 = 16.0f;

  #pragma unroll
  for (int sub=0; sub<2; ++sub){
    const int qt = sub ? pair : (15-pair);
    const int qbase = qt*128 + half*64;
    const int qg = qbase + w*16 + ln;
    short8 qf[2];
    #pragma unroll
    for (int kkI=0;kkI<2;++kkI)
      qf[kkI] = *(const short8*)&Qb[((size_t)b*S + qg)*1024 + h*64 + kkI*32 + quad*8];

    const char* cl = classes + ((size_t)b*32 + qt*2 + half)*32;
    float rs = 0.f;
    f32x4 acc[4];
    #pragma unroll
    for (int ct=0;ct<4;++ct) acc[ct] = f32x4{0.f,0.f,0.f,0.f};

    for (int kp=0; kp<8; ++kp){
      const int kt0 = 2*kp;
      const char a0=cl[2*kt0], a1=cl[2*kt0+1], b0c=cl[2*kt0+2], b1c=cl[2*kt0+3];
      if (a0==2 && a1==2 && b0c==2 && b1c==2) continue;    // dead pair: exact skip
      const bool nm[2] = { (a0|a1)==0, (b0c|b1c)==0 };
      __syncthreads();
      #pragma unroll
      for (int tI=0;tI<2;++tI){
        const int k0 = (kt0+tI)*128;
        stage128x64_sw(Kb + ((size_t)b*S + k0)*1024 + h*64, Ks[tI], 1024, w, lane);
        stage64x128_sw(Vb + ((size_t)b*1024 + h*64)*S + k0, Vs[tI], S, w, lane);
      }
      __syncthreads();

      // S^T + softmax-exp for both tiles (independent chains -> ILP)
      unsigned pk[2][8][2];
      #pragma unroll
      for (int tI=0;tI<2;++tI){
        const int k0 = (kt0+tI)*128;
        #pragma unroll
        for (int t=0;t<8;++t){
          f32x4 s = f32x4{0.f,0.f,0.f,0.f};
          #pragma unroll
          for (int kkI=0;kkI<2;++kkI)
            s = MFMA16(*frag64(Ks[tI], t*16+ln, kkI*4 + quad), qf[kkI], s);
          float e[4];
          if (nm[tI]){
            #pragma unroll
            for (int r=0;r<4;++r) e[r] = EXP2F(s[r] - C2);
          } else {
            #pragma unroll
            for (int r=0;r<4;++r){
              const int kg = k0 + t*16 + quad*4 + r;
              const float m = qk_mask[((size_t)b*S + kg)*S + qg] + k_mask[(size_t)b*S + kg];
              e[r] = EXP2F(fmaf(m, LOG2E, s[r]) - C2);
            }
          }
          rs += (e[0]+e[1]) + (e[2]+e[3]);
          pk[tI][t][0] = pack_bf16(e[0], e[1]);
          pk[tI][t][1] = pack_bf16(e[2], e[3]);
        }
      }
      // PV for both tiles
      const int srcA = (quad&1)*32 + ln, srcB = srcA + 16;
      const bool hi = (quad>>1)&1;
      #pragma unroll
      for (int tI=0;tI<2;++tI){
        #pragma unroll
        for (int c=0;c<4;++c){
          unsigned a0s = __shfl((int)pk[tI][2*c][0],   srcA, 64);
          unsigned a1s = __shfl((int)pk[tI][2*c][1],   srcA, 64);
          unsigned a2s = __shfl((int)pk[tI][2*c][0],   srcB, 64);
          unsigned a3s = __shfl((int)pk[tI][2*c][1],   srcB, 64);
          unsigned b0s = __shfl((int)pk[tI][2*c+1][0], srcA, 64);
          unsigned b1s = __shfl((int)pk[tI][2*c+1][1], srcA, 64);
          unsigned b2s = __shfl((int)pk[tI][2*c+1][0], srcB, 64);
          unsigned b3s = __shfl((int)pk[tI][2*c+1][1], srcB, 64);
          short8 pf;
          ((unsigned*)&pf)[0] = hi ? b0s : a0s;
          ((unsigned*)&pf)[1] = hi ? b1s : a1s;
          ((unsigned*)&pf)[2] = hi ? b2s : a2s;
          ((unsigned*)&pf)[3] = hi ? b3s : a3s;
          #pragma unroll
          for (int ct=0;ct<4;++ct)
            acc[ct] = MFMA16(*frag128(Vs[tI], ct*16+ln, c*4 + quad), pf, acc[ct]);
        }
      }
    }
    rs += __shfl_xor(rs, 16, 64);
    rs += __shfl_xor(rs, 32, 64);
    const float rinv = 1.0f / rs;
    #pragma unroll
    for (int ct=0;ct<4;++ct){
      short4v o4;
      #pragma unroll
      for (int r=0;r<4;++r) o4[r] = (short)f2b(acc[ct][r] * rinv);
      *(short4v*)&Ot[((size_t)b*S + qg)*1024 + h*64 + ct*16 + quad*4] = o4;
    }
  }
}

extern "C" void kernel_launch(void* const* d_in, const int* in_sizes, int n_in,
                              void* d_out, int out_size, void* d_ws, size_t ws_size,
                              hipStream_t stream)
{
  const float* q   = (const float*)d_in[0];
  const float* k   = (const float*)d_in[1];
  const float* v   = (const float*)d_in[2];
  const float* qkm = (const float*)d_in[3];
  const float* km  = (const float*)d_in[4];
  const float* Wq  = (const float*)d_in[5];
  const float* bq  = (const float*)d_in[6];
  const float* Wk  = (const float*)d_in[7];
  const float* bk  = (const float*)d_in[8];
  const float* Wv  = (const float*)d_in[9];
  const float* bv  = (const float*)d_in[10];
  const float* Wo  = (const float*)d_in[11];
  const float* bo  = (const float*)d_in[12];
  float* out = (float*)d_out;

  const size_t nAct = (size_t)2*2048*1024;   // 4M elems per activation buffer
  const int   nW   = 1024*1024;

  u16* A0 = (u16*)d_ws;          // qT, later attn output Ot
  u16* A1 = A0 + nAct;           // kT
  u16* A2 = A1 + nAct;           // vT
  u16* A3 = A2 + nAct;           // Qb
  u16* A4 = A3 + nAct;           // Kb
  u16* A5 = A4 + nAct;           // Vb
  u16* W16 = A5 + nAct;          // Wq16|Wk16|Wv16|Wo16
  char* classes = (char*)(W16 + (size_t)4*nW);   // 2 KB
  u16* Wo16 = W16 + (size_t)3*nW;

  dim3 blk(256);
  hipMemsetAsync(out, 0, (size_t)out_size*sizeof(float), stream);
  prep      <<<dim3(7168), blk, 0, stream>>>(q, k, v, qkm, km, Wq, Wk, Wv, Wo,
                                             W16, classes, A0, A1, A2);
  proj      <<<dim3(768),  blk, 0, stream>>>(A0, A1, A2, W16, bq, bk, bv, A3, A4, A5);
  attn      <<<dim3(512),  blk, 0, stream>>>(A3, A4, A5, qkm, km, classes, A0);
  gemm_out64<<<dim3(16,16,4), blk, 0, stream>>>(Wo16, A0, bo, out);
}